// Round 1
// baseline (64.298 us; speedup 1.0000x reference)
//
#include <hip/hip_runtime.h>

#define MAXLEN 768
#define DMODEL 512
// conv output length T = MAXLEN - KSIZE + 1 = 766

__global__ __launch_bounds__(256) void patch_embed_kernel(
    const float* __restrict__ x,
    const int*   __restrict__ lengths,
    const float* __restrict__ w,   // [DMODEL][3] row-major
    const float* __restrict__ b,   // [DMODEL]
    float*       __restrict__ out, // [N][DMODEL]
    int n_rows)
{
    const int lane = threadIdx.x & 63;
    const int row  = (int)((blockIdx.x * blockDim.x + threadIdx.x) >> 6);
    if (row >= n_rows) return;

    const float* xr = x + (size_t)row * MAXLEN;
    const int L = lengths[row];

    // --- masked row sum + edge elements ---
    float s = 0.0f;
    float e0 = 0.0f, e1 = 0.0f, e766 = 0.0f, e767 = 0.0f;
#pragma unroll
    for (int j = 0; j < 3; ++j) {
        const int p = 4 * (lane + 64 * j);           // 0..764, step 4, coalesced
        const float4 v = *reinterpret_cast<const float4*>(xr + p);
        const float v0 = (p + 0 < L) ? v.x : 0.0f;
        const float v1 = (p + 1 < L) ? v.y : 0.0f;
        const float v2 = (p + 2 < L) ? v.z : 0.0f;
        const float v3 = (p + 3 < L) ? v.w : 0.0f;
        s += (v0 + v1) + (v2 + v3);
        if (j == 0 && lane == 0)  { e0 = v0; e1 = v1; }       // positions 0,1
        if (j == 2 && lane == 63) { e766 = v2; e767 = v3; }   // positions 766,767
    }

    // wave-64 tree reduction
#pragma unroll
    for (int off = 32; off > 0; off >>= 1)
        s += __shfl_xor(s, off, 64);
    e0   = __shfl(e0, 0, 64);
    e1   = __shfl(e1, 0, 64);
    e766 = __shfl(e766, 63, 64);
    e767 = __shfl(e767, 63, 64);

    const float inv = 1.0f / 766.0f;
    const float m0 = (s - e766 - e767) * inv;
    const float m1 = (s - e0 - e767) * inv;
    const float m2 = (s - e0 - e1) * inv;

    // --- epilogue: out[row, d] = b[d] + m0*w[d,0] + m1*w[d,1] + m2*w[d,2] ---
    float* orow = out + (size_t)row * DMODEL;
#pragma unroll
    for (int j = 0; j < 2; ++j) {
        const int d = 4 * lane + 256 * j;            // 8 outputs/lane, coalesced
        // w + 3*d is 16B-aligned: 3*d = 12*lane (+768), 12*4B = 48B multiple of 16
        const float4 wa = *reinterpret_cast<const float4*>(w + 3 * d + 0);
        const float4 wb = *reinterpret_cast<const float4*>(w + 3 * d + 4);
        const float4 wc = *reinterpret_cast<const float4*>(w + 3 * d + 8);
        const float4 bb = *reinterpret_cast<const float4*>(b + d);
        float4 o;
        o.x = bb.x + m0 * wa.x + m1 * wa.y + m2 * wa.z;
        o.y = bb.y + m0 * wa.w + m1 * wb.x + m2 * wb.y;
        o.z = bb.z + m0 * wb.z + m1 * wb.w + m2 * wc.x;
        o.w = bb.w + m0 * wc.y + m1 * wc.z + m2 * wc.w;
        *reinterpret_cast<float4*>(orow + d) = o;
    }
}

extern "C" void kernel_launch(void* const* d_in, const int* in_sizes, int n_in,
                              void* d_out, int out_size, void* d_ws, size_t ws_size,
                              hipStream_t stream) {
    const float* x       = (const float*)d_in[0];
    const int*   lengths = (const int*)  d_in[1];
    const float* conv_w  = (const float*)d_in[2];
    const float* conv_b  = (const float*)d_in[3];
    float* out = (float*)d_out;

    const int n_rows = in_sizes[1];               // 65536
    const int waves_per_block = 256 / 64;         // 4 rows per block
    const int grid = (n_rows + waves_per_block - 1) / waves_per_block;

    patch_embed_kernel<<<grid, 256, 0, stream>>>(x, lengths, conv_w, conv_b, out, n_rows);
}

// Round 3
// 59.297 us; speedup vs baseline: 1.0843x; 1.0843x over previous
//
#include <hip/hip_runtime.h>

#define MAXLEN 768
#define DMODEL 512
// conv output length T = MAXLEN - KSIZE + 1 = 766

typedef float f32x4 __attribute__((ext_vector_type(4)));

__global__ __launch_bounds__(256) void patch_embed_kernel(
    const float* __restrict__ x,
    const int*   __restrict__ lengths,
    const float* __restrict__ w,   // [DMODEL][3] row-major
    const float* __restrict__ b,   // [DMODEL]
    float*       __restrict__ out, // [N][DMODEL]
    int n_rows)
{
    const int lane = threadIdx.x & 63;
    const int row  = (int)((blockIdx.x * blockDim.x + threadIdx.x) >> 6);
    if (row >= n_rows) return;

    const float* xr = x + (size_t)row * MAXLEN;
    const int L = lengths[row];

    // --- issue all 3 streaming loads up front (nontemporal: read-once) ---
    const f32x4 va = __builtin_nontemporal_load(reinterpret_cast<const f32x4*>(xr + 4 * lane));
    const f32x4 vb = __builtin_nontemporal_load(reinterpret_cast<const f32x4*>(xr + 4 * lane + 256));
    const f32x4 vc = __builtin_nontemporal_load(reinterpret_cast<const f32x4*>(xr + 4 * lane + 512));

    // --- masked partial sums (3 independent chains for ILP) ---
    float e0 = 0.0f, e1 = 0.0f, e766 = 0.0f, e767 = 0.0f;
    float sa, sb, sc;
    {
        const int p = 4 * lane;
        const float v0 = (p + 0 < L) ? va.x : 0.0f;
        const float v1 = (p + 1 < L) ? va.y : 0.0f;
        const float v2 = (p + 2 < L) ? va.z : 0.0f;
        const float v3 = (p + 3 < L) ? va.w : 0.0f;
        sa = (v0 + v1) + (v2 + v3);
        if (lane == 0) { e0 = v0; e1 = v1; }
    }
    {
        const int p = 4 * lane + 256;
        const float v0 = (p + 0 < L) ? vb.x : 0.0f;
        const float v1 = (p + 1 < L) ? vb.y : 0.0f;
        const float v2 = (p + 2 < L) ? vb.z : 0.0f;
        const float v3 = (p + 3 < L) ? vb.w : 0.0f;
        sb = (v0 + v1) + (v2 + v3);
    }
    {
        const int p = 4 * lane + 512;
        const float v0 = (p + 0 < L) ? vc.x : 0.0f;
        const float v1 = (p + 1 < L) ? vc.y : 0.0f;
        const float v2 = (p + 2 < L) ? vc.z : 0.0f;
        const float v3 = (p + 3 < L) ? vc.w : 0.0f;
        sc = (v0 + v1) + (v2 + v3);
        if (lane == 63) { e766 = v2; e767 = v3; }
    }
    float s = (sa + sb) + sc;

    // wave-64 tree reduction
#pragma unroll
    for (int off = 32; off > 0; off >>= 1)
        s += __shfl_xor(s, off, 64);
    e0   = __shfl(e0, 0, 64);
    e1   = __shfl(e1, 0, 64);
    e766 = __shfl(e766, 63, 64);
    e767 = __shfl(e767, 63, 64);

    const float inv = 1.0f / 766.0f;
    const float m0 = (s - e766 - e767) * inv;
    const float m1 = (s - e0 - e767) * inv;
    const float m2 = (s - e0 - e1) * inv;

    // --- epilogue: out[row, d] = b[d] + m0*w[d,0] + m1*w[d,1] + m2*w[d,2] ---
    float* orow = out + (size_t)row * DMODEL;
#pragma unroll
    for (int j = 0; j < 2; ++j) {
        const int d = 4 * lane + 256 * j;            // 8 outputs/lane, coalesced
        const f32x4 wa = *reinterpret_cast<const f32x4*>(w + 3 * d + 0);
        const f32x4 wb = *reinterpret_cast<const f32x4*>(w + 3 * d + 4);
        const f32x4 wc = *reinterpret_cast<const f32x4*>(w + 3 * d + 8);
        const f32x4 bb = *reinterpret_cast<const f32x4*>(b + d);
        f32x4 o;
        o.x = bb.x + m0 * wa.x + m1 * wa.y + m2 * wa.z;
        o.y = bb.y + m0 * wa.w + m1 * wb.x + m2 * wb.y;
        o.z = bb.z + m0 * wb.z + m1 * wb.w + m2 * wc.x;
        o.w = bb.w + m0 * wc.y + m1 * wc.z + m2 * wc.w;
        __builtin_nontemporal_store(o, reinterpret_cast<f32x4*>(orow + d));
    }
}

extern "C" void kernel_launch(void* const* d_in, const int* in_sizes, int n_in,
                              void* d_out, int out_size, void* d_ws, size_t ws_size,
                              hipStream_t stream) {
    const float* x       = (const float*)d_in[0];
    const int*   lengths = (const int*)  d_in[1];
    const float* conv_w  = (const float*)d_in[2];
    const float* conv_b  = (const float*)d_in[3];
    float* out = (float*)d_out;

    const int n_rows = in_sizes[1];               // 65536
    const int waves_per_block = 256 / 64;         // 4 rows per block
    const int grid = (n_rows + waves_per_block - 1) / waves_per_block;

    patch_embed_kernel<<<grid, 256, 0, stream>>>(x, lengths, conv_w, conv_b, out, n_rows);
}